// Round 3
// baseline (1332.317 us; speedup 1.0000x reference)
//
#include <hip/hip_runtime.h>

namespace {
constexpr int I_N   = 512;
constexpr int R_N   = 16384;
constexpr int NTOT  = I_N + R_N;      // 16896
constexpr int M     = 64;
constexpr int ZW    = NTOT;           // permanently-zero pad word (masked neighbors)
constexpr int N_OUT = 10;
constexpr int G     = 256;            // one block per CU
constexpr int T     = 1024;
constexpr int TW    = G * T / 64;     // 4096 waves
constexpr int BARW  = 320;            // barrier region words

// workspace layout (bytes), all regions 16B aligned
constexpr size_t OFF_ADJ = 0;                              // NTOT*8 u32
constexpr size_t OFF_LUT = OFF_ADJ + (size_t)NTOT * 32;    // NTOT*8 u32
constexpr size_t OFF_WPK = OFF_LUT + (size_t)NTOT * 32;    // 1024 u32
constexpr size_t OFF_XPK = OFF_WPK + 4096;                 // 2048 u32
constexpr size_t OFF_INJ = OFF_XPK + 8192;                 // 32*512 u64
constexpr size_t OFF_BAR = OFF_INJ + 131072;               // BARW u32
constexpr size_t OFF_S0  = OFF_BAR + (size_t)BARW * 4;     // (NTOT+2) u64
constexpr size_t OFF_S1  = OFF_S0 + (size_t)(NTOT + 2) * 8;
}

// ---- prep: pack LUT rows to bits; adjacency entry = neighbor BYTE offset (masked -> ZW) ----
__global__ __launch_bounds__(256) void prep_big(
    const int* __restrict__ adj, const int* __restrict__ deg,
    const float* __restrict__ lut, unsigned* __restrict__ adjenc,
    unsigned* __restrict__ lutpk)
{
  int gid = blockIdx.x * 256 + threadIdx.x;
  if (gid >= NTOT * 8) return;
  int n = gid >> 3, k = gid & 7;
  unsigned nb = (k < deg[n]) ? (unsigned)adj[gid] : (unsigned)ZW;
  adjenc[gid] = nb << 3;   // byte offset into u64 state array
  const float4* lp = reinterpret_cast<const float4*>(lut + (size_t)n * 256 + k * 32);
  unsigned w = 0;
  #pragma unroll
  for (int j = 0; j < 8; ++j) {
    float4 v = lp[j];
    w |= (v.x > 0.5f ? 1u : 0u) << (4 * j + 0);
    w |= (v.y > 0.5f ? 1u : 0u) << (4 * j + 1);
    w |= (v.z > 0.5f ? 1u : 0u) << (4 * j + 2);
    w |= (v.w > 0.5f ? 1u : 0u) << (4 * j + 3);
  }
  lutpk[gid] = w;
}

// ---- prep: pack w_in columns, x words (transposed [sc][m]), init state, zero barrier ----
__global__ __launch_bounds__(256) void prep_small(
    const float* __restrict__ x, const float* __restrict__ w_in,
    const float* __restrict__ init, unsigned* __restrict__ wpk,
    unsigned* __restrict__ xpk2, unsigned long long* __restrict__ s0,
    unsigned long long* __restrict__ s1, unsigned* __restrict__ bar)
{
  int gid = blockIdx.x * 256 + threadIdx.x;
  if (gid < 1024) {                       // wpk[c*512+i], bit b = w_in[c*32+b][i]
    int c = gid >> 9, i = gid & 511;
    unsigned w = 0;
    for (int b = 0; b < 32; ++b)
      w |= (w_in[(c * 32 + b) * 512 + i] > 0.5f ? 1u : 0u) << b;
    wpk[gid] = w;
  } else if (gid < 3072) {                // j = m*32 + s*2 + c  ->  xpk2[(s*2+c)*64 + m]
    int j = gid - 1024;
    const float* xp = x + (size_t)j * 32;
    unsigned w = 0;
    for (int b = 0; b < 32; ++b) w |= (xp[b] > 0.5f ? 1u : 0u) << b;
    xpk2[(j & 31) * 64 + (j >> 5)] = w;
  } else if (gid < 3072 + NTOT) {         // bit-sliced init: all 64 batch bits identical
    int n = gid - 3072;
    s0[n] = (init[n] > 0.5f) ? ~0ull : 0ull;
  } else if (gid == 3072 + NTOT) {
    s0[ZW] = 0ull;
  } else if (gid == 3072 + NTOT + 1) {
    s1[ZW] = 0ull;
  } else if (gid < 3072 + NTOT + 2 + BARW) {
    bar[gid - (3072 + NTOT + 2)] = 0u;    // barrier counters/sense zeroed every call
  }
}

// ---- prep: bit-sliced injection table inj[sc][i]; sc==0 folded into S0 ----
__global__ __launch_bounds__(512) void inj_pack(
    const unsigned* __restrict__ wpk, const unsigned* __restrict__ xpk2,
    unsigned long long* __restrict__ inj, unsigned long long* __restrict__ s0)
{
  int wv = (blockIdx.x * 512 + threadIdx.x) >> 6;   // 0..255
  int lane = threadIdx.x & 63;                      // lane = batch m
  int sc = wv >> 3;                                 // 8 waves per sc
  int c  = sc & 1;
  unsigned xw = xpk2[sc * 64 + lane];
  int i0 = (wv & 7) * 64;
  for (int j = 0; j < 64; ++j) {
    int i = i0 + j;
    unsigned wb = wpk[c * 512 + i];
    unsigned long long bb = __ballot((__popc(xw & wb) & 1) != 0);
    if (lane == 0) {
      inj[(size_t)sc * 512 + i] = bb;
      if (sc == 0) s0[i] ^= bb;                     // initial injection
    }
  }
}

// ---- two-level device-scope grid barrier (monotonic phase; no resets) ----
// bar[g*32] g=0..7: group counters (128B apart); bar[256]: top; bar[288]: sense
__device__ __forceinline__ void grid_barrier(unsigned* bar, unsigned phase)
{
  __syncthreads();                       // all block stores drained (vmcnt 0)
  if (threadIdx.x == 0) {
    __threadfence();                     // release: make our writes agent-visible
    unsigned g = (unsigned)blockIdx.x >> 5;
    unsigned r = __hip_atomic_fetch_add(&bar[g * 32], 1u, __ATOMIC_ACQ_REL,
                                        __HIP_MEMORY_SCOPE_AGENT);
    if (r == phase * 32u - 1u) {         // last of my group of 32
      unsigned rt = __hip_atomic_fetch_add(&bar[256], 1u, __ATOMIC_ACQ_REL,
                                           __HIP_MEMORY_SCOPE_AGENT);
      if (rt == phase * 8u - 1u)         // last group overall
        __hip_atomic_store(&bar[288], phase, __ATOMIC_RELEASE,
                           __HIP_MEMORY_SCOPE_AGENT);
    }
    while (__hip_atomic_load(&bar[288], __ATOMIC_RELAXED,
                             __HIP_MEMORY_SCOPE_AGENT) < phase)
      __builtin_amdgcn_s_sleep(1);
    __threadfence();                     // acquire: invalidate L1/L2 for fresh reads
  }
  __syncthreads();
}

// ---- main kernel: 64 ticks, software grid barrier, lanes = batches ----
__global__ __launch_bounds__(1024) void reservoir_main(
    const unsigned* __restrict__ adjenc, const unsigned* __restrict__ lutpk,
    const unsigned long long* __restrict__ inj,
    unsigned long long* __restrict__ s0, unsigned long long* __restrict__ s1,
    unsigned* __restrict__ bar)
{
  const int lane = threadIdx.x & 63;
  const int wv = (int)((blockIdx.x * (unsigned)T + threadIdx.x) >> 6);

  for (int tt = 0; tt < 64; ++tt) {
    const unsigned long long* src = (tt & 1) ? s1 : s0;
    unsigned long long*       dst = (tt & 1) ? s0 : s1;
    const bool injNext = (tt & 1) && (tt < 63);
    const unsigned long long* injn = inj + (size_t)((tt + 1) >> 1) * 512;
    const char* sp = (const char*)src;

    for (int ii = 0; ii < 5; ++ii) {
      int n = wv + ii * TW;
      if (n < NTOT) {
        const uint4* ap = reinterpret_cast<const uint4*>(adjenc + ((size_t)n << 3));
        uint4 A = ap[0], B = ap[1];
        unsigned long long w0 = *(const unsigned long long*)(sp + A.x);
        unsigned long long w1 = *(const unsigned long long*)(sp + A.y);
        unsigned long long w2 = *(const unsigned long long*)(sp + A.z);
        unsigned long long w3 = *(const unsigned long long*)(sp + A.w);
        unsigned long long w4 = *(const unsigned long long*)(sp + B.x);
        unsigned long long w5 = *(const unsigned long long*)(sp + B.y);
        unsigned long long w6 = *(const unsigned long long*)(sp + B.z);
        unsigned long long w7 = *(const unsigned long long*)(sp + B.w);
        unsigned idx;
        idx  = ((unsigned)(w0 >> lane) & 1u) << 7;
        idx |= ((unsigned)(w1 >> lane) & 1u) << 6;
        idx |= ((unsigned)(w2 >> lane) & 1u) << 5;
        idx |= ((unsigned)(w3 >> lane) & 1u) << 4;
        idx |= ((unsigned)(w4 >> lane) & 1u) << 3;
        idx |= ((unsigned)(w5 >> lane) & 1u) << 2;
        idx |= ((unsigned)(w6 >> lane) & 1u) << 1;
        idx |= ((unsigned)(w7 >> lane) & 1u);
        unsigned lv  = lutpk[((size_t)n << 3) + (idx >> 5)];
        unsigned bit = (lv >> (idx & 31u)) & 1u;
        unsigned long long bb = __ballot(bit != 0);
        if (injNext && n < I_N) bb ^= injn[n];
        if (lane == 0) dst[n] = bb;
      }
    }
    if (tt < 63) grid_barrier(bar, (unsigned)(tt + 1));
  }
}

// ---- readout: block m handles batch m (final state in s0, coherent via kernel boundary) ----
__global__ __launch_bounds__(512) void readout_k(
    const unsigned long long* __restrict__ s0, const float* __restrict__ Wout,
    const float* __restrict__ bout, float* __restrict__ out)
{
  const int m = blockIdx.x;
  const int lane = threadIdx.x & 63;
  float acc[N_OUT];
  #pragma unroll
  for (int o = 0; o < N_OUT; ++o) acc[o] = 0.f;
  for (int r = threadIdx.x; r < R_N; r += 512) {
    unsigned long long w = s0[I_N + r];
    float bf = (float)((unsigned)(w >> m) & 1u);
    #pragma unroll
    for (int o = 0; o < N_OUT; ++o)
      acc[o] += bf * Wout[(size_t)o * R_N + r];
  }
  #pragma unroll
  for (int o = 0; o < N_OUT; ++o)
    for (int off = 32; off > 0; off >>= 1)
      acc[o] += __shfl_down(acc[o], off);
  __shared__ float red[8][N_OUT];
  if (lane == 0) {
    int w8 = threadIdx.x >> 6;
    #pragma unroll
    for (int o = 0; o < N_OUT; ++o) red[w8][o] = acc[o];
  }
  __syncthreads();
  if (threadIdx.x < N_OUT) {
    float v = bout[threadIdx.x];
    for (int w8 = 0; w8 < 8; ++w8) v += red[w8][threadIdx.x];
    out[m * N_OUT + threadIdx.x] = 1.0f / (1.0f + expf(-v));
  }
}

extern "C" void kernel_launch(void* const* d_in, const int* in_sizes, int n_in,
                              void* d_out, int out_size, void* d_ws, size_t ws_size,
                              hipStream_t stream)
{
  const float* x    = (const float*)d_in[0];
  const float* w_in = (const float*)d_in[1];
  const int*   adj  = (const int*)d_in[2];
  const int*   deg  = (const int*)d_in[4];
  const float* lut  = (const float*)d_in[5];
  const float* init = (const float*)d_in[7];
  const float* Wout = (const float*)d_in[8];
  const float* bout = (const float*)d_in[9];

  char* ws = (char*)d_ws;
  unsigned*           adjenc = (unsigned*)(ws + OFF_ADJ);
  unsigned*           lutpk  = (unsigned*)(ws + OFF_LUT);
  unsigned*           wpk    = (unsigned*)(ws + OFF_WPK);
  unsigned*           xpk2   = (unsigned*)(ws + OFF_XPK);
  unsigned long long* inj    = (unsigned long long*)(ws + OFF_INJ);
  unsigned*           bar    = (unsigned*)(ws + OFF_BAR);
  unsigned long long* s0     = (unsigned long long*)(ws + OFF_S0);
  unsigned long long* s1     = (unsigned long long*)(ws + OFF_S1);

  hipLaunchKernelGGL(prep_big, dim3((NTOT * 8 + 255) / 256), dim3(256), 0, stream,
                     adj, deg, lut, adjenc, lutpk);
  hipLaunchKernelGGL(prep_small, dim3((3072 + NTOT + 2 + BARW + 255) / 256), dim3(256),
                     0, stream, x, w_in, init, wpk, xpk2, s0, s1, bar);
  hipLaunchKernelGGL(inj_pack, dim3(32), dim3(512), 0, stream, wpk, xpk2, inj, s0);
  hipLaunchKernelGGL(reservoir_main, dim3(G), dim3(T), 0, stream,
                     adjenc, lutpk, inj, s0, s1, bar);
  hipLaunchKernelGGL(readout_k, dim3(M), dim3(512), 0, stream,
                     s0, Wout, bout, (float*)d_out);
}

// Round 4
// 804.321 us; speedup vs baseline: 1.6564x; 1.6564x over previous
//
#include <hip/hip_runtime.h>

namespace {
constexpr int I_N   = 512;
constexpr int R_N   = 16384;
constexpr int NTOT  = I_N + R_N;      // 16896
constexpr int M     = 64;
constexpr int ZW    = NTOT;           // permanently-zero pad word (masked neighbors)
constexpr int N_OUT = 10;
constexpr int G     = 256;            // one block per CU (co-resident: required for barrier)
constexpr int T     = 512;
constexpr int TW2   = G * T / 64;     // 2048 waves
constexpr int BARW  = 320;            // barrier region words

// workspace layout (bytes), all regions 16B aligned
constexpr size_t OFF_ADJ = 0;                              // NTOT*8 u32
constexpr size_t OFF_LUT = OFF_ADJ + (size_t)NTOT * 32;    // NTOT*8 u32
constexpr size_t OFF_WPK = OFF_LUT + (size_t)NTOT * 32;    // 1024 u32
constexpr size_t OFF_XPK = OFF_WPK + 4096;                 // 2048 u32
constexpr size_t OFF_INJ = OFF_XPK + 8192;                 // 32*512 u64
constexpr size_t OFF_BAR = OFF_INJ + 131072;               // BARW u32
constexpr size_t OFF_S0  = OFF_BAR + (size_t)BARW * 4;     // (NTOT+2) u64
constexpr size_t OFF_S1  = OFF_S0 + (size_t)(NTOT + 2) * 8;

using u64 = unsigned long long;
}

// scope-coherent state access: sc0+sc1 -> bypass L1/L2, talk to the coherence point.
// No cache-invalidate fences anywhere; read-only tables stay L2-hot.
__device__ __forceinline__ u64 ldst(const void* p) {
  return __hip_atomic_load((const u64*)p, __ATOMIC_RELAXED, __HIP_MEMORY_SCOPE_SYSTEM);
}
__device__ __forceinline__ void stst(u64* p, u64 v) {
  __hip_atomic_store(p, v, __ATOMIC_RELAXED, __HIP_MEMORY_SCOPE_SYSTEM);
}

// ---- prep: pack LUT rows to bits; adjacency entry = neighbor BYTE offset (masked -> ZW) ----
__global__ __launch_bounds__(256) void prep_big(
    const int* __restrict__ adj, const int* __restrict__ deg,
    const float* __restrict__ lut, unsigned* __restrict__ adjenc,
    unsigned* __restrict__ lutpk)
{
  int gid = blockIdx.x * 256 + threadIdx.x;
  if (gid >= NTOT * 8) return;
  int n = gid >> 3, k = gid & 7;
  unsigned nb = (k < deg[n]) ? (unsigned)adj[gid] : (unsigned)ZW;
  adjenc[gid] = nb << 3;   // byte offset into u64 state array
  const float4* lp = reinterpret_cast<const float4*>(lut + (size_t)n * 256 + k * 32);
  unsigned w = 0;
  #pragma unroll
  for (int j = 0; j < 8; ++j) {
    float4 v = lp[j];
    w |= (v.x > 0.5f ? 1u : 0u) << (4 * j + 0);
    w |= (v.y > 0.5f ? 1u : 0u) << (4 * j + 1);
    w |= (v.z > 0.5f ? 1u : 0u) << (4 * j + 2);
    w |= (v.w > 0.5f ? 1u : 0u) << (4 * j + 3);
  }
  lutpk[gid] = w;
}

// ---- prep: pack w_in columns, x words (transposed [sc][m]), init state, zero barrier ----
__global__ __launch_bounds__(256) void prep_small(
    const float* __restrict__ x, const float* __restrict__ w_in,
    const float* __restrict__ init, unsigned* __restrict__ wpk,
    unsigned* __restrict__ xpk2, u64* __restrict__ s0,
    u64* __restrict__ s1, unsigned* __restrict__ bar)
{
  int gid = blockIdx.x * 256 + threadIdx.x;
  if (gid < 1024) {                       // wpk[c*512+i], bit b = w_in[c*32+b][i]
    int c = gid >> 9, i = gid & 511;
    unsigned w = 0;
    for (int b = 0; b < 32; ++b)
      w |= (w_in[(c * 32 + b) * 512 + i] > 0.5f ? 1u : 0u) << b;
    wpk[gid] = w;
  } else if (gid < 3072) {                // j = m*32 + s*2 + c  ->  xpk2[(s*2+c)*64 + m]
    int j = gid - 1024;
    const float* xp = x + (size_t)j * 32;
    unsigned w = 0;
    for (int b = 0; b < 32; ++b) w |= (xp[b] > 0.5f ? 1u : 0u) << b;
    xpk2[(j & 31) * 64 + (j >> 5)] = w;
  } else if (gid < 3072 + NTOT) {         // bit-sliced init: all 64 batch bits identical
    int n = gid - 3072;
    s0[n] = (init[n] > 0.5f) ? ~0ull : 0ull;
  } else if (gid == 3072 + NTOT) {
    s0[ZW] = 0ull;
  } else if (gid == 3072 + NTOT + 1) {
    s1[ZW] = 0ull;
  } else if (gid < 3072 + NTOT + 2 + BARW) {
    bar[gid - (3072 + NTOT + 2)] = 0u;    // barrier counters/sense zeroed every call
  }
}

// ---- prep: bit-sliced injection table inj[sc][i]; sc==0 folded into S0 ----
__global__ __launch_bounds__(512) void inj_pack(
    const unsigned* __restrict__ wpk, const unsigned* __restrict__ xpk2,
    u64* __restrict__ inj, u64* __restrict__ s0)
{
  int wv = (blockIdx.x * 512 + threadIdx.x) >> 6;   // 0..255
  int lane = threadIdx.x & 63;                      // lane = batch m
  int sc = wv >> 3;                                 // 8 waves per sc
  int c  = sc & 1;
  unsigned xw = xpk2[sc * 64 + lane];
  int i0 = (wv & 7) * 64;
  for (int j = 0; j < 64; ++j) {
    int i = i0 + j;
    unsigned wb = wpk[c * 512 + i];
    u64 bb = __ballot((__popc(xw & wb) & 1) != 0);
    if (lane == 0) {
      inj[(size_t)sc * 512 + i] = bb;
      if (sc == 0) s0[i] ^= bb;                     // initial injection
    }
  }
}

// ---- two-level grid barrier: NO cache fences (data is write-through sc0sc1) ----
// bar[g*32] g=0..7: group counters (128B apart); bar[256]: top; bar[288]: sense
__device__ __forceinline__ void grid_barrier(unsigned* bar, unsigned phase)
{
  __syncthreads();   // per-wave s_waitcnt vmcnt(0): all block stores acked at L3
  if (threadIdx.x == 0) {
    asm volatile("" ::: "memory");
    unsigned g = (unsigned)blockIdx.x >> 5;
    unsigned r = __hip_atomic_fetch_add(&bar[g * 32], 1u, __ATOMIC_RELAXED,
                                        __HIP_MEMORY_SCOPE_SYSTEM);
    if (r == phase * 32u - 1u) {         // last of my group of 32
      unsigned rt = __hip_atomic_fetch_add(&bar[256], 1u, __ATOMIC_RELAXED,
                                           __HIP_MEMORY_SCOPE_SYSTEM);
      if (rt == phase * 8u - 1u)         // last group overall
        __hip_atomic_store(&bar[288], phase, __ATOMIC_RELAXED,
                           __HIP_MEMORY_SCOPE_SYSTEM);
    }
    while (__hip_atomic_load(&bar[288], __ATOMIC_RELAXED,
                             __HIP_MEMORY_SCOPE_SYSTEM) < phase)
      __builtin_amdgcn_s_sleep(2);
    asm volatile("" ::: "memory");
  }
  __syncthreads();
}

// ---- main kernel: 64 ticks, software grid barrier, lanes = batches ----
__global__ __launch_bounds__(512) void reservoir_main(
    const unsigned* __restrict__ adjenc, const unsigned* __restrict__ lutpk,
    const u64* __restrict__ inj, u64* __restrict__ s0, u64* __restrict__ s1,
    unsigned* __restrict__ bar)
{
  const int lane = threadIdx.x & 63;
  const int wv = (int)((blockIdx.x * (unsigned)T + threadIdx.x) >> 6);
  const int n0 = (int)(((long long)wv * NTOT) / TW2);
  const int n1 = (int)(((long long)(wv + 1) * NTOT) / TW2);

  for (int tt = 0; tt < 64; ++tt) {
    const u64* src = (tt & 1) ? s1 : s0;
    u64*       dst = (tt & 1) ? s0 : s1;
    const bool injNext = (tt & 1) && (tt < 63);
    const u64* injn = inj + (size_t)((tt + 1) >> 1) * 512;
    const char* sp = (const char*)src;

    for (int n = n0; n < n1; ++n) {
      const uint4* ap = reinterpret_cast<const uint4*>(adjenc + ((size_t)n << 3));
      uint4 A = ap[0], B = ap[1];
      u64 w0 = ldst(sp + A.x);
      u64 w1 = ldst(sp + A.y);
      u64 w2 = ldst(sp + A.z);
      u64 w3 = ldst(sp + A.w);
      u64 w4 = ldst(sp + B.x);
      u64 w5 = ldst(sp + B.y);
      u64 w6 = ldst(sp + B.z);
      u64 w7 = ldst(sp + B.w);
      unsigned idx;
      idx  = ((unsigned)(w0 >> lane) & 1u) << 7;
      idx |= ((unsigned)(w1 >> lane) & 1u) << 6;
      idx |= ((unsigned)(w2 >> lane) & 1u) << 5;
      idx |= ((unsigned)(w3 >> lane) & 1u) << 4;
      idx |= ((unsigned)(w4 >> lane) & 1u) << 3;
      idx |= ((unsigned)(w5 >> lane) & 1u) << 2;
      idx |= ((unsigned)(w6 >> lane) & 1u) << 1;
      idx |= ((unsigned)(w7 >> lane) & 1u);
      unsigned lv  = lutpk[((size_t)n << 3) + (idx >> 5)];
      unsigned bit = (lv >> (idx & 31u)) & 1u;
      u64 bb = __ballot(bit != 0);
      if (injNext && n < I_N) bb ^= injn[n];
      if (lane == 0) stst(dst + n, bb);
    }
    if (tt < 63) grid_barrier(bar, (unsigned)(tt + 1));
  }
}

// ---- readout: block m handles batch m (visibility via kernel boundary) ----
__global__ __launch_bounds__(512) void readout_k(
    const u64* __restrict__ s0, const float* __restrict__ Wout,
    const float* __restrict__ bout, float* __restrict__ out)
{
  const int m = blockIdx.x;
  const int lane = threadIdx.x & 63;
  float acc[N_OUT];
  #pragma unroll
  for (int o = 0; o < N_OUT; ++o) acc[o] = 0.f;
  for (int r = threadIdx.x; r < R_N; r += 512) {
    u64 w = s0[I_N + r];
    float bf = (float)((unsigned)(w >> m) & 1u);
    #pragma unroll
    for (int o = 0; o < N_OUT; ++o)
      acc[o] += bf * Wout[(size_t)o * R_N + r];
  }
  #pragma unroll
  for (int o = 0; o < N_OUT; ++o)
    for (int off = 32; off > 0; off >>= 1)
      acc[o] += __shfl_down(acc[o], off);
  __shared__ float red[8][N_OUT];
  if (lane == 0) {
    int w8 = threadIdx.x >> 6;
    #pragma unroll
    for (int o = 0; o < N_OUT; ++o) red[w8][o] = acc[o];
  }
  __syncthreads();
  if (threadIdx.x < N_OUT) {
    float v = bout[threadIdx.x];
    for (int w8 = 0; w8 < 8; ++w8) v += red[w8][threadIdx.x];
    out[m * N_OUT + threadIdx.x] = 1.0f / (1.0f + expf(-v));
  }
}

extern "C" void kernel_launch(void* const* d_in, const int* in_sizes, int n_in,
                              void* d_out, int out_size, void* d_ws, size_t ws_size,
                              hipStream_t stream)
{
  const float* x    = (const float*)d_in[0];
  const float* w_in = (const float*)d_in[1];
  const int*   adj  = (const int*)d_in[2];
  const int*   deg  = (const int*)d_in[4];
  const float* lut  = (const float*)d_in[5];
  const float* init = (const float*)d_in[7];
  const float* Wout = (const float*)d_in[8];
  const float* bout = (const float*)d_in[9];

  char* ws = (char*)d_ws;
  unsigned* adjenc = (unsigned*)(ws + OFF_ADJ);
  unsigned* lutpk  = (unsigned*)(ws + OFF_LUT);
  unsigned* wpk    = (unsigned*)(ws + OFF_WPK);
  unsigned* xpk2   = (unsigned*)(ws + OFF_XPK);
  u64*      inj    = (u64*)(ws + OFF_INJ);
  unsigned* bar    = (unsigned*)(ws + OFF_BAR);
  u64*      s0     = (u64*)(ws + OFF_S0);
  u64*      s1     = (u64*)(ws + OFF_S1);

  hipLaunchKernelGGL(prep_big, dim3((NTOT * 8 + 255) / 256), dim3(256), 0, stream,
                     adj, deg, lut, adjenc, lutpk);
  hipLaunchKernelGGL(prep_small, dim3((3072 + NTOT + 2 + BARW + 255) / 256), dim3(256),
                     0, stream, x, w_in, init, wpk, xpk2, s0, s1, bar);
  hipLaunchKernelGGL(inj_pack, dim3(32), dim3(512), 0, stream, wpk, xpk2, inj, s0);
  hipLaunchKernelGGL(reservoir_main, dim3(G), dim3(T), 0, stream,
                     adjenc, lutpk, inj, s0, s1, bar);
  hipLaunchKernelGGL(readout_k, dim3(M), dim3(512), 0, stream,
                     s0, Wout, bout, (float*)d_out);
}

// Round 5
// 358.954 us; speedup vs baseline: 3.7117x; 2.2407x over previous
//
#include <hip/hip_runtime.h>

namespace {
constexpr int I_N   = 512;
constexpr int R_N   = 16384;
constexpr int NTOT  = I_N + R_N;      // 16896
constexpr int ZW    = NTOT;           // permanently-zero state byte (masked neighbors)
constexpr int N_OUT = 10;
constexpr int G     = 256;            // one block per CU (pinned via 84KB dyn LDS)
constexpr int T     = 1024;
constexpr int UTOT  = NTOT / 8;       // 2112 units of 8 nodes
constexpr int STRIDE = 16960;         // per-group state stride (bytes)
constexpr size_t SBUF = (size_t)8 * STRIDE;

// workspace layout (bytes)
constexpr size_t OFF_ADJ = 0;                              // NTOT*8 u32 = 540672
constexpr size_t OFF_LUT = OFF_ADJ + (size_t)NTOT * 32;    // NTOT*8 u32 = 540672
constexpr size_t OFF_WPK = OFF_LUT + (size_t)NTOT * 32;    // 1024 u32
constexpr size_t OFF_XPK = OFF_WPK + 4096;                 // 2048 u32
constexpr size_t OFF_INJ = OFF_XPK + 8192;                 // 8*32*512 u8 = 131072
constexpr size_t OFF_BAR = OFF_INJ + 131072;               // 1024 u32
constexpr size_t OFF_ST  = OFF_BAR + 4096;                 // 2 * 8 * STRIDE

using u64 = unsigned long long;
using u8  = unsigned char;
}

// system-scope helpers (barrier bookkeeping only — MALL-coherent)
__device__ __forceinline__ unsigned afa(unsigned* p) {
  return __hip_atomic_fetch_add(p, 1u, __ATOMIC_RELAXED, __HIP_MEMORY_SCOPE_SYSTEM);
}
__device__ __forceinline__ unsigned lda(const unsigned* p) {
  return __hip_atomic_load(p, __ATOMIC_RELAXED, __HIP_MEMORY_SCOPE_SYSTEM);
}
__device__ __forceinline__ void sta(unsigned* p, unsigned v) {
  __hip_atomic_store(p, v, __ATOMIC_RELAXED, __HIP_MEMORY_SCOPE_SYSTEM);
}

// ---- prep: pack LUT rows to bits; adjacency entry = neighbor byte index (masked -> ZW) ----
__global__ __launch_bounds__(256) void prep_big(
    const int* __restrict__ adj, const int* __restrict__ deg,
    const float* __restrict__ lut, unsigned* __restrict__ adjenc,
    unsigned* __restrict__ lutpk)
{
  int gid = blockIdx.x * 256 + threadIdx.x;
  if (gid >= NTOT * 8) return;
  int n = gid >> 3, k = gid & 7;
  adjenc[gid] = (k < deg[n]) ? (unsigned)adj[gid] : (unsigned)ZW;
  const float4* lp = reinterpret_cast<const float4*>(lut + (size_t)n * 256 + k * 32);
  unsigned w = 0;
  #pragma unroll
  for (int j = 0; j < 8; ++j) {
    float4 v = lp[j];
    w |= (v.x > 0.5f ? 1u : 0u) << (4 * j + 0);
    w |= (v.y > 0.5f ? 1u : 0u) << (4 * j + 1);
    w |= (v.z > 0.5f ? 1u : 0u) << (4 * j + 2);
    w |= (v.w > 0.5f ? 1u : 0u) << (4 * j + 3);
  }
  lutpk[gid] = w;
}

// ---- prep: pack w_in columns, x words (transposed [sc][m]), zero barrier region ----
__global__ __launch_bounds__(256) void prep_small(
    const float* __restrict__ x, const float* __restrict__ w_in,
    unsigned* __restrict__ wpk, unsigned* __restrict__ xpk2,
    unsigned* __restrict__ bar)
{
  int gid = blockIdx.x * 256 + threadIdx.x;
  if (gid < 1024) {                       // wpk[c*512+i], bit b = w_in[c*32+b][i]
    int c = gid >> 9, i = gid & 511;
    unsigned w = 0;
    for (int b = 0; b < 32; ++b)
      w |= (w_in[(c * 32 + b) * 512 + i] > 0.5f ? 1u : 0u) << b;
    wpk[gid] = w;
  } else if (gid < 3072) {                // j = m*32 + s*2 + c  ->  xpk2[(s*2+c)*64 + m]
    int j = gid - 1024;
    const float* xp = x + (size_t)j * 32;
    unsigned w = 0;
    for (int b = 0; b < 32; ++b) w |= (xp[b] > 0.5f ? 1u : 0u) << b;
    xpk2[(j & 31) * 64 + (j >> 5)] = w;
  } else if (gid < 4096) {
    bar[gid - 3072] = 0u;                 // barrier + registration counters
  }
}

// ---- prep: u8-sliced injection inj8[g][sc][n] (bit b = batch g*8+b) ----
__global__ __launch_bounds__(256) void prep_inj8(
    const unsigned* __restrict__ wpk, const unsigned* __restrict__ xpk2,
    u8* __restrict__ inj8)
{
  int wv = (blockIdx.x * 256 + threadIdx.x) >> 6;   // 0..255
  int lane = threadIdx.x & 63;
  int g = wv >> 5, sc = wv & 31, c = sc & 1;
  int b = lane & 7;
  unsigned xw = xpk2[sc * 64 + g * 8 + b];
  for (int it = 0; it < 64; ++it) {
    int nbase = it * 8;
    int n = nbase + (lane >> 3);
    unsigned wb = wpk[c * 512 + n];
    u64 bb = __ballot((__popc(xw & wb) & 1) != 0);
    if (lane == 0)
      *(u64*)(inj8 + ((size_t)(g * 32 + sc) << 9) + nbase) = bb;
  }
}

// ---- prep: initial state per group (init bits, fold sc=0 injection), zero pad byte ----
__global__ __launch_bounds__(256) void prep_state(
    const float* __restrict__ init, const u8* __restrict__ inj8,
    u8* __restrict__ st)
{
  int n = blockIdx.x * 256 + threadIdx.x;   // 66*256 = 16896 exactly
  int g = blockIdx.y;
  u8 v = (init[n] > 0.5f) ? (u8)0xFF : (u8)0x00;
  if (n < I_N) v ^= inj8[((size_t)(g * 32) << 9) + n];
  st[(size_t)g * STRIDE + n] = v;
  if (n == 0) {
    st[(size_t)g * STRIDE + ZW] = 0;          // buffer A pad
    st[SBUF + (size_t)g * STRIDE + ZW] = 0;   // buffer B pad
  }
}

// ---- main: 8 XCD-local groups of 8 batches; per-XCD barriers; sc0 gather blobs ----
__global__ __launch_bounds__(1024) void reservoir_main(
    const unsigned* __restrict__ adjenc, const unsigned* __restrict__ lutpk,
    const u8* __restrict__ inj8, u8* __restrict__ st, unsigned* __restrict__ bar)
{
  extern __shared__ char dynpad[];           // occupancy pin (84000 B -> 1 block/CU)
  (void)dynpad;
  __shared__ int s_grp, s_slot, s_cnt;
  const int tid = threadIdx.x;
  const int lane = tid & 63;
  const int wv16 = tid >> 6;

  // --- self-organize by physical XCD ---
  if (tid == 0) {
    unsigned xcc;
    asm volatile("s_getreg_b32 %0, hwreg(HW_REG_XCC_ID)" : "=s"(xcc));
    int g = (int)(xcc & 7u);
    s_grp = g;
    s_slot = (int)afa(&bar[32 + g * 16]);    // register in my group
  }
  __syncthreads();
  const int g = s_grp;

  // one-time global barrier: all 256 blocks registered
  __syncthreads();
  if (tid == 0) {
    unsigned r = afa(&bar[0]);
    if (r == (unsigned)(G - 1)) sta(&bar[16], 1u);
    while (lda(&bar[16]) < 1u) __builtin_amdgcn_s_sleep(2);
  }
  __syncthreads();
  if (tid == 0) s_cnt = (int)lda(&bar[32 + g * 16]);
  __syncthreads();
  const unsigned kcnt = (unsigned)s_cnt;
  const int slot = s_slot;

  // node-unit range for this block (units of 8 nodes)
  const unsigned u0 = (unsigned)(((u64)slot * UTOT) / kcnt);
  const unsigned u1 = (unsigned)(((u64)(slot + 1) * UTOT) / kcnt);

  const u8* bA = st + (size_t)g * STRIDE;
  const u8* bB = st + SBUF + (size_t)g * STRIDE;
  const uint4* adj4 = reinterpret_cast<const uint4*>(adjenc);
  const unsigned bv = (unsigned)(lane & 7);

  for (int tt = 0; tt < 64; ++tt) {
    const char* srcg = (const char*)((tt & 1) ? bB : bA);
    char*       dstg = (char*)((tt & 1) ? bA : bB);
    const bool injNow = (tt & 1) && (tt < 63);
    const u8* injp = inj8 + ((size_t)(g * 32 + ((tt + 1) >> 1)) << 9);

    for (unsigned u = u0 + wv16; u < u1; u += 16) {
      const int nbase = (int)(u << 3);
      const int n = nbase + (lane >> 3);
      uint4 A = adj4[(size_t)n * 2];
      uint4 B = adj4[(size_t)n * 2 + 1];
      unsigned c0, c1, c2, c3, c4, c5, c6, c7;
      // 8 L1-bypass byte gathers (XCD-L2 coherence point), one wait
      asm volatile(
        "global_load_ubyte %0, %8, %16 sc0\n\t"
        "global_load_ubyte %1, %9, %16 sc0\n\t"
        "global_load_ubyte %2, %10, %16 sc0\n\t"
        "global_load_ubyte %3, %11, %16 sc0\n\t"
        "global_load_ubyte %4, %12, %16 sc0\n\t"
        "global_load_ubyte %5, %13, %16 sc0\n\t"
        "global_load_ubyte %6, %14, %16 sc0\n\t"
        "global_load_ubyte %7, %15, %16 sc0\n\t"
        "s_waitcnt vmcnt(0)"
        : "=&v"(c0), "=&v"(c1), "=&v"(c2), "=&v"(c3),
          "=&v"(c4), "=&v"(c5), "=&v"(c6), "=&v"(c7)
        : "v"(A.x), "v"(A.y), "v"(A.z), "v"(A.w),
          "v"(B.x), "v"(B.y), "v"(B.z), "v"(B.w),
          "s"(srcg)
        : "memory");
      unsigned idx = (c0 >> bv) & 1u;
      idx = (idx << 1) | ((c1 >> bv) & 1u);
      idx = (idx << 1) | ((c2 >> bv) & 1u);
      idx = (idx << 1) | ((c3 >> bv) & 1u);
      idx = (idx << 1) | ((c4 >> bv) & 1u);
      idx = (idx << 1) | ((c5 >> bv) & 1u);
      idx = (idx << 1) | ((c6 >> bv) & 1u);
      idx = (idx << 1) | ((c7 >> bv) & 1u);
      unsigned lv  = lutpk[((size_t)n << 3) + (idx >> 5)];
      unsigned bit = (lv >> (idx & 31u)) & 1u;
      u64 bb = __ballot(bit != 0);
      if (lane == 0) {
        if (injNow && nbase < I_N) bb ^= *(const u64*)(injp + nbase);
        *(u64*)(dstg + nbase) = bb;   // normal store -> dirty in my XCD's L2
      }
    }

    // per-XCD barrier (phase-monotonic)
    if (tt < 63) {
      const unsigned p = (unsigned)(tt + 1);
      __syncthreads();               // drains vmcnt(0): all block stores acked in L2
      if (tid == 0) {
        unsigned r = afa(&bar[256 + g * 32]);
        if (r == p * kcnt - 1u) sta(&bar[512 + g * 32], p);
        while (lda(&bar[512 + g * 32]) < p) __builtin_amdgcn_s_sleep(2);
      }
      __syncthreads();
    }
  }
}

// ---- readout: block m = batch (g = m>>3, bit b = m&7); final state in buffer A ----
__global__ __launch_bounds__(512) void readout_k(
    const u8* __restrict__ st, const float* __restrict__ Wout,
    const float* __restrict__ bout, float* __restrict__ out)
{
  const int m = blockIdx.x;
  const int gg = m >> 3, b = m & 7;
  const int lane = threadIdx.x & 63;
  const u8* sp = st + (size_t)gg * STRIDE + I_N;
  float acc[N_OUT];
  #pragma unroll
  for (int o = 0; o < N_OUT; ++o) acc[o] = 0.f;
  for (int r = threadIdx.x; r < R_N; r += 512) {
    float bf = (float)((sp[r] >> b) & 1u);
    #pragma unroll
    for (int o = 0; o < N_OUT; ++o)
      acc[o] += bf * Wout[(size_t)o * R_N + r];
  }
  #pragma unroll
  for (int o = 0; o < N_OUT; ++o)
    for (int off = 32; off > 0; off >>= 1)
      acc[o] += __shfl_down(acc[o], off);
  __shared__ float red[8][N_OUT];
  if (lane == 0) {
    int w8 = threadIdx.x >> 6;
    #pragma unroll
    for (int o = 0; o < N_OUT; ++o) red[w8][o] = acc[o];
  }
  __syncthreads();
  if (threadIdx.x < N_OUT) {
    float v = bout[threadIdx.x];
    for (int w8 = 0; w8 < 8; ++w8) v += red[w8][threadIdx.x];
    out[m * N_OUT + threadIdx.x] = 1.0f / (1.0f + expf(-v));
  }
}

extern "C" void kernel_launch(void* const* d_in, const int* in_sizes, int n_in,
                              void* d_out, int out_size, void* d_ws, size_t ws_size,
                              hipStream_t stream)
{
  const float* x    = (const float*)d_in[0];
  const float* w_in = (const float*)d_in[1];
  const int*   adj  = (const int*)d_in[2];
  const int*   deg  = (const int*)d_in[4];
  const float* lut  = (const float*)d_in[5];
  const float* init = (const float*)d_in[7];
  const float* Wout = (const float*)d_in[8];
  const float* bout = (const float*)d_in[9];

  char* ws = (char*)d_ws;
  unsigned* adjenc = (unsigned*)(ws + OFF_ADJ);
  unsigned* lutpk  = (unsigned*)(ws + OFF_LUT);
  unsigned* wpk    = (unsigned*)(ws + OFF_WPK);
  unsigned* xpk2   = (unsigned*)(ws + OFF_XPK);
  u8*       inj8   = (u8*)(ws + OFF_INJ);
  unsigned* bar    = (unsigned*)(ws + OFF_BAR);
  u8*       st     = (u8*)(ws + OFF_ST);

  hipLaunchKernelGGL(prep_big, dim3((NTOT * 8 + 255) / 256), dim3(256), 0, stream,
                     adj, deg, lut, adjenc, lutpk);
  hipLaunchKernelGGL(prep_small, dim3(16), dim3(256), 0, stream,
                     x, w_in, wpk, xpk2, bar);
  hipLaunchKernelGGL(prep_inj8, dim3(64), dim3(256), 0, stream, wpk, xpk2, inj8);
  hipLaunchKernelGGL(prep_state, dim3(66, 8), dim3(256), 0, stream, init, inj8, st);
  hipLaunchKernelGGL(reservoir_main, dim3(G), dim3(T), 84000, stream,
                     adjenc, lutpk, inj8, st, bar);
  hipLaunchKernelGGL(readout_k, dim3(64), dim3(512), 0, stream,
                     st, Wout, bout, (float*)d_out);
}

// Round 6
// 292.631 us; speedup vs baseline: 4.5529x; 1.2266x over previous
//
#include <hip/hip_runtime.h>

namespace {
constexpr int I_N   = 512;
constexpr int R_N   = 16384;
constexpr int NTOT  = I_N + R_N;      // 16896
constexpr int ZW    = NTOT;           // permanently-zero state byte (masked neighbors)
constexpr int N_OUT = 10;
constexpr int G     = 248;            // < 256: co-residency slack (CWSR outlier fix)
constexpr int T     = 1024;
constexpr int UTOT  = NTOT / 8;       // 2112 units of 8 nodes
constexpr int STRIDE = 16960;         // per-group state stride (bytes), 16B aligned
constexpr size_t SBUF = (size_t)8 * STRIDE;

// workspace layout (bytes)
constexpr size_t OFF_ADJ = 0;                              // NTOT*8 u32
constexpr size_t OFF_LUT = OFF_ADJ + (size_t)NTOT * 32;    // NTOT*8 u32
constexpr size_t OFF_WPK = OFF_LUT + (size_t)NTOT * 32;    // 1024 u32
constexpr size_t OFF_XPK = OFF_WPK + 4096;                 // 2048 u32
constexpr size_t OFF_INJ = OFF_XPK + 8192;                 // 8*32*512 u8
constexpr size_t OFF_BAR = OFF_INJ + 131072;               // 1024 u32
constexpr size_t OFF_ST  = OFF_BAR + 4096;                 // 2 * 8 * STRIDE

using u64 = unsigned long long;
using u8  = unsigned char;

// prep_all gid segmentation
constexpr int PA_BIG = NTOT * 8;        // adj/lut packing          135168
constexpr int PA_W   = PA_BIG;          // + wpk                    1024
constexpr int PA_X   = PA_W + 1024;     // + xpk2                   2048
constexpr int PA_B   = PA_X + 2048;     // + bar zero               1024
constexpr int PA_S   = PA_B + 1024;     // + state init             8*NTOT
constexpr int PA_TOT = PA_S + 8 * NTOT; // = 274432 = 1072*256
}

// ---- cross-XCD (MALL) atomics: registration only ----
__device__ __forceinline__ unsigned afa_sys(unsigned* p) {
  return __hip_atomic_fetch_add(p, 1u, __ATOMIC_RELAXED, __HIP_MEMORY_SCOPE_SYSTEM);
}
__device__ __forceinline__ unsigned lda_sys(const unsigned* p) {
  return __hip_atomic_load(p, __ATOMIC_RELAXED, __HIP_MEMORY_SCOPE_SYSTEM);
}
__device__ __forceinline__ void sta_sys(unsigned* p, unsigned v) {
  __hip_atomic_store(p, v, __ATOMIC_RELAXED, __HIP_MEMORY_SCOPE_SYSTEM);
}
// ---- XCD-local (L2) barrier ops: all participants share one XCD by construction ----
__device__ __forceinline__ unsigned afa_l2(unsigned* p) {  // global_atomic_add, no sc1
  return __hip_atomic_fetch_add(p, 1u, __ATOMIC_RELAXED, __HIP_MEMORY_SCOPE_WORKGROUP);
}
__device__ __forceinline__ unsigned lda_l2(const unsigned* p) {  // sc0 load -> L2
  return __hip_atomic_load(p, __ATOMIC_RELAXED, __HIP_MEMORY_SCOPE_AGENT);
}
__device__ __forceinline__ void sta_l2(unsigned* p, unsigned v) {  // write-through -> L2
  __hip_atomic_store(p, v, __ATOMIC_RELAXED, __HIP_MEMORY_SCOPE_WORKGROUP);
}

// ---- fused prep: adj/lut pack + wpk + xpk2 + bar zero + state(n>=512) init ----
__global__ __launch_bounds__(256) void prep_all(
    const int* __restrict__ adj, const int* __restrict__ deg,
    const float* __restrict__ lut, const float* __restrict__ x,
    const float* __restrict__ w_in, const float* __restrict__ init,
    unsigned* __restrict__ adjenc, unsigned* __restrict__ lutpk,
    unsigned* __restrict__ wpk, unsigned* __restrict__ xpk2,
    unsigned* __restrict__ bar, u8* __restrict__ st)
{
  int gid = blockIdx.x * 256 + threadIdx.x;
  if (gid < PA_BIG) {
    int n = gid >> 3, k = gid & 7;
    adjenc[gid] = (k < deg[n]) ? (unsigned)adj[gid] : (unsigned)ZW;
    const float4* lp = reinterpret_cast<const float4*>(lut + (size_t)n * 256 + k * 32);
    unsigned w = 0;
    #pragma unroll
    for (int j = 0; j < 8; ++j) {
      float4 v = lp[j];
      w |= (v.x > 0.5f ? 1u : 0u) << (4 * j + 0);
      w |= (v.y > 0.5f ? 1u : 0u) << (4 * j + 1);
      w |= (v.z > 0.5f ? 1u : 0u) << (4 * j + 2);
      w |= (v.w > 0.5f ? 1u : 0u) << (4 * j + 3);
    }
    lutpk[gid] = w;
  } else if (gid < PA_X) {                // wpk[c*512+i], bit b = w_in[c*32+b][i]
    int i2 = gid - PA_W;
    int c = i2 >> 9, i = i2 & 511;
    unsigned w = 0;
    for (int b = 0; b < 32; ++b)
      w |= (w_in[(c * 32 + b) * 512 + i] > 0.5f ? 1u : 0u) << b;
    wpk[i2] = w;
  } else if (gid < PA_B) {                // j = m*32+s*2+c -> xpk2[(s*2+c)*64+m]
    int j = gid - PA_X;
    const float* xp = x + (size_t)j * 32;
    unsigned w = 0;
    for (int b = 0; b < 32; ++b) w |= (xp[b] > 0.5f ? 1u : 0u) << b;
    xpk2[(j & 31) * 64 + (j >> 5)] = w;
  } else if (gid < PA_S) {
    bar[gid - PA_B] = 0u;                 // barrier + registration words
  } else {
    int j = gid - PA_S;
    int g = j / NTOT;
    int n = j - g * NTOT;
    if (n >= I_N)
      st[(size_t)g * STRIDE + n] = (init[n] > 0.5f) ? (u8)0xFF : (u8)0x00;
    if (n == 0) {
      st[(size_t)g * STRIDE + ZW] = 0;          // buffer A pad
      st[SBUF + (size_t)g * STRIDE + ZW] = 0;   // buffer B pad
    }
  }
}

// ---- prep: inj8[g][sc][n]; sc==0 waves also write buffer-A state for n<512 ----
__global__ __launch_bounds__(256) void inj_pack(
    const unsigned* __restrict__ wpk, const unsigned* __restrict__ xpk2,
    const float* __restrict__ init, u8* __restrict__ inj8, u8* __restrict__ st)
{
  int wv = (blockIdx.x * 256 + threadIdx.x) >> 6;   // 0..255
  int lane = threadIdx.x & 63;
  int g = wv >> 5, sc = wv & 31, c = sc & 1, b = lane & 7;
  unsigned xw = xpk2[sc * 64 + g * 8 + b];
  for (int it = 0; it < 64; ++it) {
    int nbase = it * 8, n = nbase + (lane >> 3);
    unsigned wb = wpk[c * 512 + n];
    u64 bb = __ballot((__popc(xw & wb) & 1) != 0);
    if (sc == 0) {
      u64 ib = __ballot(init[n] > 0.5f);
      if (lane == 0)
        *(u64*)(st + (size_t)g * STRIDE + nbase) = ib ^ bb;
    }
    if (lane == 0)
      *(u64*)(inj8 + ((size_t)(g * 32 + sc) << 9) + nbase) = bb;
  }
}

// ---- per-XCD barrier: arrivals + phase word live in the XCD's own L2 ----
__device__ __forceinline__ void xcd_barrier(unsigned* bar, int g, unsigned kcnt,
                                            unsigned p)
{
  __syncthreads();   // per-wave s_waitcnt vmcnt(0): block's state stores acked in L2
  if (threadIdx.x == 0) {
    asm volatile("" ::: "memory");
    unsigned r = afa_l2(&bar[256 + g * 32]);
    if (r == p * kcnt - 1u) sta_l2(&bar[512 + g * 32], p);
    while (lda_l2(&bar[512 + g * 32]) < p) __builtin_amdgcn_s_sleep(1);
    asm volatile("" ::: "memory");
  }
  __syncthreads();
}

// ---- main: LDS state mirror per CU; gathers from LDS; per-XCD L2 barrier ----
__global__ __launch_bounds__(1024) void reservoir_main(
    const unsigned* __restrict__ adjenc, const unsigned* __restrict__ lutpk,
    const u8* __restrict__ inj8, u8* __restrict__ st, unsigned* __restrict__ bar)
{
  extern __shared__ char dynpad[];           // occupancy pin -> 1 block/CU
  (void)dynpad;
  __shared__ __align__(16) u8 sstate[STRIDE];
  __shared__ int s_grp, s_slot, s_cnt;
  const int tid = threadIdx.x;
  const int lane = tid & 63;
  const int wv16 = tid >> 6;

  // --- self-organize by physical XCD ---
  if (tid == 0) {
    unsigned xcc;
    asm volatile("s_getreg_b32 %0, hwreg(HW_REG_XCC_ID)" : "=s"(xcc));
    int g = (int)(xcc & 7u);
    s_grp = g;
    s_slot = (int)afa_sys(&bar[32 + g * 16]);
    asm volatile("s_waitcnt vmcnt(0)" ::: "memory");  // reg-add landed BEFORE count
    unsigned r = afa_sys(&bar[0]);
    if (r == (unsigned)(G - 1)) sta_sys(&bar[16], 1u);
    while (lda_sys(&bar[16]) < 1u) __builtin_amdgcn_s_sleep(2);
    s_cnt = (int)lda_sys(&bar[32 + g * 16]);
  }
  __syncthreads();
  const int g = s_grp;
  const unsigned kcnt = (unsigned)s_cnt;
  const int slot = s_slot;
  const unsigned u0 = (unsigned)(((u64)slot * UTOT) / kcnt);
  const unsigned u1 = (unsigned)(((u64)(slot + 1) * UTOT) / kcnt);

  u8* bA = st + (size_t)g * STRIDE;
  u8* bB = st + SBUF + (size_t)g * STRIDE;
  const unsigned bv = (unsigned)(lane & 7);

  for (int tt = 0; tt < 64; ++tt) {
    const u8* srcg = (tt & 1) ? bB : bA;
    u8*       dstg = (tt & 1) ? bA : bB;

    // --- refresh LDS mirror from local L2 (sc0: bypass stale L1) ---
    {
      uint4 v0, v1;
      const u8* p0 = srcg + tid * 16;
      asm volatile("global_load_dwordx4 %0, %1, off sc0" : "=v"(v0) : "v"(p0));
      const bool tail = tid < (STRIDE - 16384) / 16;   // 36 threads
      const u8* p1 = srcg + 16384 + tid * 16;
      if (tail)
        asm volatile("global_load_dwordx4 %0, %1, off sc0" : "=v"(v1) : "v"(p1));
      asm volatile("s_waitcnt vmcnt(0)" ::: "memory");
      *reinterpret_cast<uint4*>(&sstate[tid * 16]) = v0;
      if (tail) *reinterpret_cast<uint4*>(&sstate[16384 + tid * 16]) = v1;
    }
    __syncthreads();

    const bool injNow = (tt & 1) && (tt < 63);
    const u8* injp = inj8 + ((size_t)(g * 32 + ((tt + 1) >> 1)) << 9);

    for (unsigned u = u0 + wv16; u < u1; u += 16) {
      const int nbase = (int)(u << 3);
      const int n = nbase + (lane >> 3);
      const uint4* ap = reinterpret_cast<const uint4*>(adjenc + ((size_t)n << 3));
      uint4 A = ap[0], B = ap[1];
      unsigned idx;
      idx  = ((unsigned)(sstate[A.x] >> bv) & 1u) << 7;
      idx |= ((unsigned)(sstate[A.y] >> bv) & 1u) << 6;
      idx |= ((unsigned)(sstate[A.z] >> bv) & 1u) << 5;
      idx |= ((unsigned)(sstate[A.w] >> bv) & 1u) << 4;
      idx |= ((unsigned)(sstate[B.x] >> bv) & 1u) << 3;
      idx |= ((unsigned)(sstate[B.y] >> bv) & 1u) << 2;
      idx |= ((unsigned)(sstate[B.z] >> bv) & 1u) << 1;
      idx |= ((unsigned)(sstate[B.w] >> bv) & 1u);
      unsigned lv  = lutpk[((size_t)n << 3) + (idx >> 5)];
      unsigned bit = (lv >> (idx & 31u)) & 1u;
      u64 bb = __ballot(bit != 0);
      if (lane == 0) {
        if (injNow && nbase < I_N) bb ^= *(const u64*)(injp + nbase);
        *(u64*)(dstg + nbase) = bb;   // normal store -> my XCD's L2
      }
    }
    if (tt < 63) xcd_barrier(bar, g, kcnt, (unsigned)(tt + 1));
  }
}

// ---- readout: block m = batch (g=m>>3, bit=m&7); final state in buffer A ----
__global__ __launch_bounds__(512) void readout_k(
    const u8* __restrict__ st, const float* __restrict__ Wout,
    const float* __restrict__ bout, float* __restrict__ out)
{
  const int m = blockIdx.x;
  const int gg = m >> 3, b = m & 7;
  const int lane = threadIdx.x & 63;
  const u8* sp = st + (size_t)gg * STRIDE + I_N;
  float acc[N_OUT];
  #pragma unroll
  for (int o = 0; o < N_OUT; ++o) acc[o] = 0.f;
  for (int r = threadIdx.x; r < R_N; r += 512) {
    float bf = (float)((sp[r] >> b) & 1u);
    #pragma unroll
    for (int o = 0; o < N_OUT; ++o)
      acc[o] += bf * Wout[(size_t)o * R_N + r];
  }
  #pragma unroll
  for (int o = 0; o < N_OUT; ++o)
    for (int off = 32; off > 0; off >>= 1)
      acc[o] += __shfl_down(acc[o], off);
  __shared__ float red[8][N_OUT];
  if (lane == 0) {
    int w8 = threadIdx.x >> 6;
    #pragma unroll
    for (int o = 0; o < N_OUT; ++o) red[w8][o] = acc[o];
  }
  __syncthreads();
  if (threadIdx.x < N_OUT) {
    float v = bout[threadIdx.x];
    for (int w8 = 0; w8 < 8; ++w8) v += red[w8][threadIdx.x];
    out[m * N_OUT + threadIdx.x] = 1.0f / (1.0f + expf(-v));
  }
}

extern "C" void kernel_launch(void* const* d_in, const int* in_sizes, int n_in,
                              void* d_out, int out_size, void* d_ws, size_t ws_size,
                              hipStream_t stream)
{
  const float* x    = (const float*)d_in[0];
  const float* w_in = (const float*)d_in[1];
  const int*   adj  = (const int*)d_in[2];
  const int*   deg  = (const int*)d_in[4];
  const float* lut  = (const float*)d_in[5];
  const float* init = (const float*)d_in[7];
  const float* Wout = (const float*)d_in[8];
  const float* bout = (const float*)d_in[9];

  char* ws = (char*)d_ws;
  unsigned* adjenc = (unsigned*)(ws + OFF_ADJ);
  unsigned* lutpk  = (unsigned*)(ws + OFF_LUT);
  unsigned* wpk    = (unsigned*)(ws + OFF_WPK);
  unsigned* xpk2   = (unsigned*)(ws + OFF_XPK);
  u8*       inj8   = (u8*)(ws + OFF_INJ);
  unsigned* bar    = (unsigned*)(ws + OFF_BAR);
  u8*       st     = (u8*)(ws + OFF_ST);

  hipLaunchKernelGGL(prep_all, dim3(PA_TOT / 256), dim3(256), 0, stream,
                     adj, deg, lut, x, w_in, init, adjenc, lutpk, wpk, xpk2, bar, st);
  hipLaunchKernelGGL(inj_pack, dim3(64), dim3(256), 0, stream,
                     wpk, xpk2, init, inj8, st);
  hipLaunchKernelGGL(reservoir_main, dim3(G), dim3(T), 66560, stream,
                     adjenc, lutpk, inj8, st, bar);
  hipLaunchKernelGGL(readout_k, dim3(64), dim3(512), 0, stream,
                     st, Wout, bout, (float*)d_out);
}